// Round 2
// baseline (259.481 us; speedup 1.0000x reference)
//
#include <hip/hip_runtime.h>
#include <stdint.h>

typedef unsigned short ushort_t;
typedef __attribute__((ext_vector_type(8))) short short8v;   // 8 x bf16
typedef __attribute__((ext_vector_type(4))) float f32x4;     // MFMA acc

// ws: At bf16 [16][128][512] (2 MiB) | Wt bf16 [16][512][512] (8 MiB)
#define AT_ELEMS (16u * 128u * 512u)
#define WT_ELEMS (16u * 512u * 512u)
#define WS_NEEDED ((size_t)(AT_ELEMS + WT_ELEMS) * 2u)

__host__ __device__ constexpr int ga_sign_i(int a, int b) {
  int t = a >> 1, sw = 0;
  while (t) {
    int x = t & b;
    while (x) { sw += x & 1; x >>= 1; }
    t >>= 1;
  }
  return (sw & 1) ? -1 : 1;
}

struct SignTab { int s[16][16]; };
constexpr SignTab make_tab() {
  SignTab t{};
  for (int i = 0; i < 16; i++)
    for (int j = 0; j < 16; j++) t.s[i][j] = ga_sign_i(i, j);
  return t;
}
constexpr SignTab STAB = make_tab();

__device__ __forceinline__ ushort_t f2bf(float f) {
  unsigned u = __float_as_uint(f);
  u = (u + 0x7FFFu + ((u >> 16) & 1u)) >> 16;   // RNE
  return (ushort_t)u;
}

__device__ __forceinline__ short8v neg_bf16x8(short8v v) {
  const short m = (short)0x8000;
  return v ^ (short8v){m, m, m, m, m, m, m, m};
}

// ---------------------------------------------------------------------------
// prep (unchanged, proven): At[j][b][n] = bf16(x[b,n,j]); Wt[j][u][n] = bf16(w[u,n,j])
// ---------------------------------------------------------------------------
#define PREP_XT (128 * 512)
#define PREP_TOT (PREP_XT + 512 * 512)   // 327,680 -> 1280 blocks

__global__ __launch_bounds__(256) void prep_kernel(const float* __restrict__ x,
                                                   const float* __restrict__ w,
                                                   ushort_t* __restrict__ At,
                                                   ushort_t* __restrict__ Wt) {
  int tid = blockIdx.x * 256 + threadIdx.x;
  if (tid < PREP_XT) {
    int n = tid & 511, b = tid >> 9;
    const float4* xp = (const float4*)(x + (size_t)tid * 16);
    float v[16];
#pragma unroll
    for (int qq = 0; qq < 4; qq++) {
      float4 t = xp[qq];
      v[qq * 4 + 0] = t.x; v[qq * 4 + 1] = t.y; v[qq * 4 + 2] = t.z; v[qq * 4 + 3] = t.w;
    }
#pragma unroll
    for (int j = 0; j < 16; j++)
      At[((size_t)(j * 128 + b)) * 512 + n] = f2bf(v[j]);
  } else {
    int t = tid - PREP_XT;
    int n = t & 511, u = t >> 9;
    const float4* wp = (const float4*)(w + (size_t)t * 16);
    float v[16];
#pragma unroll
    for (int qq = 0; qq < 4; qq++) {
      float4 tt = wp[qq];
      v[qq * 4 + 0] = tt.x; v[qq * 4 + 1] = tt.y; v[qq * 4 + 2] = tt.z; v[qq * 4 + 3] = tt.w;
    }
#pragma unroll
    for (int j = 0; j < 16; j++)
      Wt[((size_t)(j * 512 + u)) * 512 + n] = f2bf(v[j]);
  }
}

// ---------------------------------------------------------------------------
// gemm v3: v1's proven LDS staging pattern + T3 "minimum 2-phase" pipeline.
// Stage granularity halved to 64 n: per stage A(16i x 16b x 64n, 32 KB) +
// W(16j x 16u x 64n, 32 KB) = 64 KB -> DOUBLE-BUFFERED in 128 KB LDS.
// Per stage: issue next-stage global_load_lds FIRST, then ds_read + 128 MFMA
// on current buffer, then s_waitcnt vmcnt(0) (drains under/after the MFMA
// phase, not before it) + raw s_barrier. One barrier per stage; prefetch
// stays in flight across the entire compute phase (kills the v1 stage<->
// compute serialization that fully-exposed drains caused at 1 block/CU).
// Waves partition (n-half wn x j-half wj) instead of n-quarters: per wave
// 16 av + 8 bv ds_reads, 128 MFMA/stage, acc[16]; the existing 4-wave
// epilogue sum is partition-agnostic (disjoint n and j contributions add).
// Swizzle (slot = p ^ (row&7), 128 B rows, 3-bit XOR, bijective) and frag
// maps identical in structure to v1 -> conflict-free b128 reads, DMA-linear
// dests. Race check: stage-s writes hit buf[(s+1)&1], last read at s-1;
// reads complete before each wave's s-1 barrier, writes issue only after it.
// ---------------------------------------------------------------------------
__global__ __launch_bounds__(256, 1) void gemm_kernel(const ushort_t* __restrict__ At,
                                                      const ushort_t* __restrict__ Wt,
                                                      const float* __restrict__ bias,
                                                      float* __restrict__ out) {
  __shared__ __align__(16) ushort_t smem[65536];   // 128 KB: buf0 @0, buf1 @64 KB (A 32K | W 32K each)

  const int ut = blockIdx.x;       // 0..31
  const int bt = blockIdx.y;       // 0..7
  const int u0 = ut * 16, b0 = bt * 16;

  const int tid = threadIdx.x;
  const int wv = tid >> 6, lane = tid & 63;
  const int la = lane & 15, q = lane >> 4;
  const int wn = wv >> 1, wj = wv & 1;   // n-half, j-half

  // --- staging (DMA) thread map: 2 planes x 16 rows x 8 slots per instr ---
  const int srow2 = tid >> 3;            // 0..31
  const int ip = srow2 >> 4;             // plane parity (i = 2m + ip)
  const int row = srow2 & 15;
  const int sps = tid & 7;               // slot in the 128 B row
  const int sp = sps ^ (row & 7);        // content chunk (8 elems) at this slot

  const ushort_t* Abase = At + (size_t)(ip * 128 + b0 + row) * 512 + sp * 8;
  const ushort_t* Wbase = Wt + (size_t)(ip * 512 + u0 + row) * 512 + sp * 8;

  // --- frag read: byte offset within a 2 KB (16 row x 128 B) plane ---
  const int lbx = la * 128 + ((((wn << 2) | q) ^ (la & 7)) * 16);

  f32x4 acc[16];
#pragma unroll
  for (int k = 0; k < 16; k++) acc[k] = (f32x4){0.f, 0.f, 0.f, 0.f};

#define STAGE(BUFB, SN)                                                                       \
  do {                                                                                        \
    _Pragma("unroll")                                                                         \
    for (int m = 0; m < 8; m++) {                                                             \
      __builtin_amdgcn_global_load_lds(                                                       \
          (const __attribute__((address_space(1))) unsigned int*)(Abase + (size_t)m * 131072 + (size_t)(SN) * 64), \
          (__attribute__((address_space(3))) unsigned int*)(&smem[((BUFB) + m * 4096 + tid * 16) >> 1]),            \
          16, 0, 0);                                                                          \
      __builtin_amdgcn_global_load_lds(                                                       \
          (const __attribute__((address_space(1))) unsigned int*)(Wbase + (size_t)m * 524288 + (size_t)(SN) * 64), \
          (__attribute__((address_space(3))) unsigned int*)(&smem[((BUFB) + 32768 + m * 4096 + tid * 16) >> 1]),    \
          16, 0, 0);                                                                          \
    }                                                                                         \
  } while (0)

  // prologue: fill buf0 with stage 0; full drain + barrier once.
  STAGE(0, 0);
  __syncthreads();

#pragma unroll 1
  for (int s = 0; s < 8; s++) {
    const int cb = (s & 1) << 16;        // current buffer byte offset
    if (s < 7) STAGE(cb ^ 65536, s + 1); // prefetch next stage into other buffer

    const char* smb = (const char*)smem + cb;
    short8v av[16], nav[16];
#pragma unroll
    for (int i = 0; i < 16; i++) {
      av[i] = *(const short8v*)(smb + i * 2048 + lbx);
      nav[i] = neg_bf16x8(av[i]);
    }
#pragma unroll
    for (int jj = 0; jj < 8; jj++) {
      const int j = wj * 8 + jj;
      const short8v bvj = *(const short8v*)(smb + 32768 + j * 2048 + lbx);
#pragma unroll
      for (int k = 0; k < 16; k++) {
        const int i = j ^ k;                 // compile-time after unroll
        acc[k] = __builtin_amdgcn_mfma_f32_16x16x32_bf16(
            (STAB.s[i][j] < 0) ? nav[i] : av[i], bvj, acc[k], 0, 0, 0);
      }
    }

    // Drain own prefetch (landed under the MFMA phase), then publish.
    asm volatile("s_waitcnt vmcnt(0)" ::: "memory");
    __builtin_amdgcn_s_barrier();
  }
#undef STAGE

  // --- epilogue: cross-wave reduction + bias + coalesced float4 out ---
  float* red = (float*)smem;   // reuse first 64 KB: [wv][row16][col16][k16] f32
#pragma unroll
  for (int g = 0; g < 4; g++) {
#pragma unroll
    for (int r2 = 0; r2 < 4; r2++) {
      float4 v = make_float4(acc[g * 4 + 0][r2], acc[g * 4 + 1][r2],
                             acc[g * 4 + 2][r2], acc[g * 4 + 3][r2]);
      int orow = q * 4 + r2;                 // C/D: row = quad*4 + reg (m89)
      *(float4*)&red[(((wv * 16 + orow) * 16 + la) << 4) + g * 4] = v;
    }
  }
  __syncthreads();

  const int orow = tid >> 4, col = tid & 15;
  float4 o[4];
#pragma unroll
  for (int g = 0; g < 4; g++)
    o[g] = *(const float4*)&bias[(u0 + col) * 16 + g * 4];
#pragma unroll
  for (int w2 = 0; w2 < 4; w2++) {
#pragma unroll
    for (int g = 0; g < 4; g++) {
      float4 v = *(const float4*)&red[(((w2 * 16 + orow) * 16 + col) << 4) + g * 4];
      o[g].x += v.x; o[g].y += v.y; o[g].z += v.z; o[g].w += v.w;
    }
  }
#pragma unroll
  for (int g = 0; g < 4; g++)
    *(float4*)&out[((size_t)(b0 + orow) * 512 + (u0 + col)) * 16 + g * 4] = o[g];
}

// ---------------------------------------------------------------------------
// fallback (ws too small): exact fp32, slow but correct
// ---------------------------------------------------------------------------
__global__ __launch_bounds__(256) void naive_kernel(const float* __restrict__ x,
                                                    const float* __restrict__ w,
                                                    const float* __restrict__ bias,
                                                    float* __restrict__ out) {
  int t = blockIdx.x * 256 + threadIdx.x;
  if (t >= 128 * 512 * 16) return;
  int k = t & 15;
  int u = (t >> 4) & 511;
  int b = t >> 13;
  float sgn[16];
#pragma unroll
  for (int i = 0; i < 16; i++) sgn[i] = (float)ga_sign_i(i, i ^ k);
  float acc = bias[u * 16 + k];
  for (int n = 0; n < 512; n++) {
    const float* xp = x + ((size_t)(b * 512 + n)) * 16;
    const float* wp = w + ((size_t)(u * 512 + n)) * 16;
#pragma unroll
    for (int i = 0; i < 16; i++)
      acc += xp[i] * sgn[i] * wp[i ^ k];
  }
  out[t] = acc;
}

extern "C" void kernel_launch(void* const* d_in, const int* in_sizes, int n_in,
                              void* d_out, int out_size, void* d_ws, size_t ws_size,
                              hipStream_t stream) {
  const float* x    = (const float*)d_in[0];
  const float* w    = (const float*)d_in[1];
  const float* bias = (const float*)d_in[2];
  float* out = (float*)d_out;

  if (ws_size >= WS_NEEDED && d_ws != nullptr) {
    ushort_t* At = (ushort_t*)d_ws;
    ushort_t* Wt = At + AT_ELEMS;

    prep_kernel<<<PREP_TOT / 256, 256, 0, stream>>>(x, w, At, Wt);
    gemm_kernel<<<dim3(32, 8), 256, 0, stream>>>(At, Wt, bias, out);
  } else {
    naive_kernel<<<(128 * 512 * 16) / 256, 256, 0, stream>>>(x, w, bias, out);
  }
}